// Round 2
// baseline (8641.805 us; speedup 1.0000x reference)
//
#include <hip/hip_runtime.h>
#include <cmath>

// ---------------------------------------------------------------------------
// S2VT. Round 1: persistent cooperative kernel for all 248 LSTM steps
// (2-pipeline interleave, weights resident in LDS, grid barrier in ws),
// batched split-bf16 MFMA GEMMs for all K-independent projections.
// ---------------------------------------------------------------------------

typedef __bf16 bf16x8 __attribute__((ext_vector_type(8)));
typedef float  f32x4  __attribute__((ext_vector_type(4)));

#define LDSROW 40   // gemm_split LDS row: 32 data + 4 pad bf16 (80B stride)
#define SLOT   65536  // 128*512 elements
#define NBLK   128    // persistent grid

// ===========================================================================
// Batched GEMM with fp32-grade accuracy: A,B split to bf16 hi/lo, 3 MFMAs.
// C[M,N] = A[M,K] @ Bw[N,K]^T (+bias[n]) (+C_old if ACCUM). M % 128 == 0.
// ===========================================================================
template<bool BIAS, bool ACCUM>
__global__ __launch_bounds__(256)
void gemm_split(const float* __restrict__ A, int lda,
                const float* __restrict__ Bw, int ldb,
                float* __restrict__ C, int ldc,
                const float* __restrict__ bias,
                int M, int N, int K)
{
    (void)M;
    __shared__ __bf16 sAh[128 * LDSROW], sAl[128 * LDSROW];
    __shared__ __bf16 sBh[128 * LDSROW], sBl[128 * LDSROW];

    const int tid  = threadIdx.x;
    const int lane = tid & 63;
    const int wid  = tid >> 6;
    const int m0 = blockIdx.x * 128, n0 = blockIdx.y * 128;
    const int wm = (wid >> 1) * 64, wn = (wid & 1) * 64;
    const int lr = lane & 15, lg = lane >> 4;

    const int srow = tid >> 1;
    const int scol = (tid & 1) * 16;

    f32x4 acc[4][4];
#pragma unroll
    for (int mt = 0; mt < 4; ++mt)
#pragma unroll
        for (int nt = 0; nt < 4; ++nt) acc[mt][nt] = (f32x4)(0.0f);

    const int KT = (K + 31) >> 5;
    for (int kt = 0; kt < KT; ++kt) {
        const int k0 = kt * 32;
        {
            const float* aptr = A + (size_t)(m0 + srow) * lda + k0 + scol;
            float x[16];
            if (k0 + scol + 16 <= K) {
                const f32x4* p = (const f32x4*)aptr;
                f32x4 v0 = p[0], v1 = p[1], v2 = p[2], v3 = p[3];
#pragma unroll
                for (int j = 0; j < 4; ++j) { x[j] = v0[j]; x[4+j] = v1[j]; x[8+j] = v2[j]; x[12+j] = v3[j]; }
            } else {
#pragma unroll
                for (int j = 0; j < 16; ++j) {
                    const int kk = k0 + scol + j;
                    x[j] = (kk < K) ? aptr[j] : 0.f;
                }
            }
#pragma unroll
            for (int j = 0; j < 16; ++j) {
                const float v = x[j];
                const __bf16 h = (__bf16)v;
                sAh[srow * LDSROW + scol + j] = h;
                sAl[srow * LDSROW + scol + j] = (__bf16)(v - (float)h);
            }
        }
        {
            const int nrow = n0 + srow;
            const float* bptr = Bw + (size_t)nrow * ldb + k0 + scol;
            float x[16];
            if (nrow < N && k0 + scol + 16 <= K) {
                const f32x4* p = (const f32x4*)bptr;
                f32x4 v0 = p[0], v1 = p[1], v2 = p[2], v3 = p[3];
#pragma unroll
                for (int j = 0; j < 4; ++j) { x[j] = v0[j]; x[4+j] = v1[j]; x[8+j] = v2[j]; x[12+j] = v3[j]; }
            } else {
#pragma unroll
                for (int j = 0; j < 16; ++j) {
                    const int kk = k0 + scol + j;
                    x[j] = (nrow < N && kk < K) ? bptr[j] : 0.f;
                }
            }
#pragma unroll
            for (int j = 0; j < 16; ++j) {
                const float v = x[j];
                const __bf16 h = (__bf16)v;
                sBh[srow * LDSROW + scol + j] = h;
                sBl[srow * LDSROW + scol + j] = (__bf16)(v - (float)h);
            }
        }
        __syncthreads();

        bf16x8 ah[4], al[4], bh[4], bl[4];
#pragma unroll
        for (int t = 0; t < 4; ++t) {
            ah[t] = *(const bf16x8*)&sAh[(wm + t * 16 + lr) * LDSROW + lg * 8];
            al[t] = *(const bf16x8*)&sAl[(wm + t * 16 + lr) * LDSROW + lg * 8];
            bh[t] = *(const bf16x8*)&sBh[(wn + t * 16 + lr) * LDSROW + lg * 8];
            bl[t] = *(const bf16x8*)&sBl[(wn + t * 16 + lr) * LDSROW + lg * 8];
        }
#pragma unroll
        for (int mt = 0; mt < 4; ++mt)
#pragma unroll
            for (int nt = 0; nt < 4; ++nt) {
                f32x4 a_ = acc[mt][nt];
                a_ = __builtin_amdgcn_mfma_f32_16x16x32_bf16(ah[mt], bh[nt], a_, 0, 0, 0);
                a_ = __builtin_amdgcn_mfma_f32_16x16x32_bf16(ah[mt], bl[nt], a_, 0, 0, 0);
                a_ = __builtin_amdgcn_mfma_f32_16x16x32_bf16(al[mt], bh[nt], a_, 0, 0, 0);
                acc[mt][nt] = a_;
            }
        __syncthreads();
    }

#pragma unroll
    for (int mt = 0; mt < 4; ++mt)
#pragma unroll
        for (int nt = 0; nt < 4; ++nt)
#pragma unroll
            for (int r = 0; r < 4; ++r) {
                const int m = m0 + wm + mt * 16 + lg * 4 + r;
                const int n = n0 + wn + nt * 16 + lr;
                if (n < N) {
                    float v = acc[mt][nt][r];
                    if (BIAS) v += bias[n];
                    if (ACCUM) v += C[(size_t)m * ldc + n];
                    C[(size_t)m * ldc + n] = v;
                }
            }
}

// ===========================================================================
// Persistent recurrence kernel: 128 blocks (64 enc, 64 dec) x 256 threads.
// Enc block owns 8 hidden dims of the encoder LSTM; dec block 8 dims of the
// decoder LSTM. Weights resident in LDS as bf16 (XOR-swizzled rows).
// h broadcast between blocks as bf16 hi/lo arrays in global memory.
// ===========================================================================

__device__ __forceinline__ void gbar(unsigned* cnt, unsigned* gen)
{
    __syncthreads();
    if (threadIdx.x == 0) {
        __threadfence();  // release our block's global writes (agent scope)
        const unsigned g = __hip_atomic_load(gen, __ATOMIC_RELAXED, __HIP_MEMORY_SCOPE_AGENT);
        const unsigned a = __hip_atomic_fetch_add(cnt, 1u, __ATOMIC_ACQ_REL, __HIP_MEMORY_SCOPE_AGENT);
        if (a == NBLK - 1) {
            __hip_atomic_store(cnt, 0u, __ATOMIC_RELAXED, __HIP_MEMORY_SCOPE_AGENT);
            __hip_atomic_store(gen, g + 1u, __ATOMIC_RELEASE, __HIP_MEMORY_SCOPE_AGENT);
        } else {
            while (__hip_atomic_load(gen, __ATOMIC_ACQUIRE, __HIP_MEMORY_SCOPE_AGENT) == g)
                __builtin_amdgcn_s_sleep(1);
        }
        __threadfence();  // acquire: invalidate stale L1/L2 lines
    }
    __syncthreads();
}

// One gate-GEMM: pg[128 x 32] = [A1 | A2](hi+lo) @ sW^T for this block's 32
// gate rows. Wave w owns m-rows [w*32, w*32+32), both n-tiles.
// A-frag: lane holds A[m = base + (lane&15)][k = kt*32 + (lane>>4)*8 .. +7].
template<int KT>
__device__ __forceinline__ void gemm_phase(
    const __bf16* __restrict__ sW, float* __restrict__ pg, int K,
    const __bf16* __restrict__ s1h, const __bf16* __restrict__ s1l,
    const __bf16* __restrict__ s2h, const __bf16* __restrict__ s2l)
{
    const int lane = threadIdx.x & 63, w = threadIdx.x >> 6;
    const int lr = lane & 15, lg = lane >> 4;
    const int kf = lg * 8;
    const int mb = w * 32 + lr;

    f32x4 acc[2][2];
#pragma unroll
    for (int mt = 0; mt < 2; ++mt)
#pragma unroll
        for (int nt = 0; nt < 2; ++nt) acc[mt][nt] = (f32x4)(0.0f);

#pragma unroll 2
    for (int kt = 0; kt < KT; ++kt) {
        const int kk = kt * 32 + kf;
        const __bf16* ph; const __bf16* pl; int ko;
        if (kk < 512) { ph = s1h; pl = s1l; ko = kk; }
        else          { ph = s2h; pl = s2l; ko = kk - 512; }

        const int n0 = lr, n1 = 16 + lr;
        const bf16x8 b0 = *(const bf16x8*)&sW[(n0 * K + kt * 32 + kf) ^ ((n0 & 7) << 3)];
        const bf16x8 b1 = *(const bf16x8*)&sW[(n1 * K + kt * 32 + kf) ^ ((n1 & 7) << 3)];
#pragma unroll
        for (int mt = 0; mt < 2; ++mt) {
            const int m = mb + mt * 16;
            const bf16x8 ah = *(const bf16x8*)&ph[m * 512 + ko];
            const bf16x8 al = *(const bf16x8*)&pl[m * 512 + ko];
            acc[mt][0] = __builtin_amdgcn_mfma_f32_16x16x32_bf16(ah, b0, acc[mt][0], 0, 0, 0);
            acc[mt][0] = __builtin_amdgcn_mfma_f32_16x16x32_bf16(al, b0, acc[mt][0], 0, 0, 0);
            acc[mt][1] = __builtin_amdgcn_mfma_f32_16x16x32_bf16(ah, b1, acc[mt][1], 0, 0, 0);
            acc[mt][1] = __builtin_amdgcn_mfma_f32_16x16x32_bf16(al, b1, acc[mt][1], 0, 0, 0);
        }
    }

#pragma unroll
    for (int mt = 0; mt < 2; ++mt)
#pragma unroll
        for (int nt = 0; nt < 2; ++nt)
#pragma unroll
            for (int r = 0; r < 4; ++r)
                pg[(w * 32 + mt * 16 + lg * 4 + r) * 33 + nt * 16 + lr] = acc[mt][nt][r];
}

// Pointwise LSTM update for this block's (b, dd) pairs. Thread t owns
// b = t>>1, dd = (t&1)*4 + j, j=0..3; c[] persists in registers.
__device__ __forceinline__ void pointwise(
    const float* __restrict__ pg, const float* __restrict__ gpre,
    const float* __restrict__ bsl, float* __restrict__ c, int d0,
    __bf16* __restrict__ hhi, __bf16* __restrict__ hlo, float* __restrict__ hf32)
{
    const int tid = threadIdx.x;
    const int b = tid >> 1, hf = tid & 1;
    float add_[4][4];
    if (gpre) {
#pragma unroll
        for (int g = 0; g < 4; ++g) {
            const f32x4 v = *(const f32x4*)&gpre[b * 2048 + g * 512 + d0 + hf * 4];
#pragma unroll
            for (int j = 0; j < 4; ++j) add_[g][j] = v[j];
        }
    } else {
#pragma unroll
        for (int g = 0; g < 4; ++g)
#pragma unroll
            for (int j = 0; j < 4; ++j) add_[g][j] = bsl[g * 8 + hf * 4 + j];
    }
#pragma unroll
    for (int j = 0; j < 4; ++j) {
        const int dd = hf * 4 + j;
        const float pi = pg[b * 33 +  0 + dd] + add_[0][j];
        const float pf = pg[b * 33 +  8 + dd] + add_[1][j];
        const float pG = pg[b * 33 + 16 + dd] + add_[2][j];
        const float po = pg[b * 33 + 24 + dd] + add_[3][j];
        const float ig = 1.f / (1.f + __expf(-pi));
        const float fg = 1.f / (1.f + __expf(-pf));
        const float gg = tanhf(pG);
        const float og = 1.f / (1.f + __expf(-po));
        c[j] = fg * c[j] + ig * gg;
        const float h = og * tanhf(c[j]);
        const int off = b * 512 + d0 + dd;
        const __bf16 hh = (__bf16)h;
        hhi[off] = hh;
        hlo[off] = (__bf16)(h - (float)hh);
        if (hf32) hf32[off] = h;
    }
}

__global__ __launch_bounds__(256, 1)
void recurrence_kernel(const float* __restrict__ gpreE, const float* __restrict__ gpre2,
                       const float* __restrict__ We_hh, const float* __restrict__ Wd_ih,
                       const float* __restrict__ Wd_hh,
                       const float* __restrict__ be, const float* __restrict__ bd,
                       __bf16* encHi, __bf16* encLo, __bf16* padHi, __bf16* padLo,
                       __bf16* dHi, __bf16* dLo, float* doutW,
                       unsigned* bar_cnt, unsigned* bar_gen)
{
    __shared__ __bf16 sW[32 * 1024];   // 64 KB (enc uses half: K=512)
    __shared__ float  pg[128 * 33];    // 16.5 KB gate pre-acts
    __shared__ float  bsl[32];

    const int  bid    = blockIdx.x;
    const bool is_dec = bid >= 64;
    const int  d0     = (is_dec ? bid - 64 : bid) * 8;
    const int  tid    = threadIdx.x;
    const int  K      = is_dec ? 1024 : 512;

    // ---- stage resident weights (gate rows n = g*8+dd -> global g*512+d0+dd)
    for (int idx = tid; idx < 32 * K; idx += 256) {
        const int nn = idx / K;
        const int kk = idx - nn * K;
        const int gr = (nn >> 3) * 512 + d0 + (nn & 7);
        float wv;
        if (!is_dec) wv = We_hh[(size_t)gr * 512 + kk];
        else         wv = (kk < 512) ? Wd_ih[(size_t)gr * 1024 + kk]
                                     : Wd_hh[(size_t)gr * 512 + kk - 512];
        sW[(nn * K + kk) ^ ((nn & 7) << 3)] = (__bf16)wv;
    }
    if (tid < 32) bsl[tid] = (is_dec ? bd : be)[(tid >> 3) * 512 + d0 + (tid & 7)];
    __syncthreads();

    float c[4] = {0.f, 0.f, 0.f, 0.f};

    // ---- pipeline A: phase p runs enc step p (p<80) and dec1 step p-1 (p>=1)
    for (int p = 0; p <= 80; ++p) {
        if (!is_dec) {
            if (p < 80) {
                gemm_phase<16>(sW, pg, 512,
                               encHi + (p & 1) * SLOT, encLo + (p & 1) * SLOT,
                               nullptr, nullptr);
                __syncthreads();
                pointwise(pg, gpreE + (size_t)p * 262144, bsl, c, d0,
                          encHi + ((p + 1) & 1) * SLOT, encLo + ((p + 1) & 1) * SLOT, nullptr);
            }
        } else {
            if (p >= 1) {
                const int t = p - 1;
                gemm_phase<32>(sW, pg, 1024,
                               encHi + (p & 1) * SLOT, encLo + (p & 1) * SLOT,
                               dHi + (t & 1) * SLOT, dLo + (t & 1) * SLOT);
                __syncthreads();
                pointwise(pg, nullptr, bsl, c, d0,
                          dHi + ((t + 1) & 1) * SLOT, dLo + ((t + 1) & 1) * SLOT, nullptr);
            }
        }
        gbar(bar_cnt, bar_gen);
    }

    // ---- pipeline transition: dec swaps in Wd_ih[:, 512:1024]
    if (is_dec) {
        for (int idx = tid; idx < 32 * 512; idx += 256) {
            const int nn = idx >> 9, kk = idx & 511;
            const int gr = (nn >> 3) * 512 + d0 + (nn & 7);
            sW[(nn * 1024 + kk) ^ ((nn & 7) << 3)] = (__bf16)Wd_ih[(size_t)gr * 1024 + 512 + kk];
        }
    }
    __syncthreads();

    // ---- pipeline B: phase q runs enc-pad step q (q<44) and dec2 step q-1
    for (int q = 0; q <= 44; ++q) {
        if (!is_dec) {
            if (q < 44) {
                const __bf16* sh = (q == 0) ? encHi : padHi + (q & 1) * SLOT;
                const __bf16* sl = (q == 0) ? encLo : padLo + (q & 1) * SLOT;
                gemm_phase<16>(sW, pg, 512, sh, sl, nullptr, nullptr);
                __syncthreads();
                pointwise(pg, nullptr, bsl, c, d0,
                          padHi + ((q + 1) & 1) * SLOT, padLo + ((q + 1) & 1) * SLOT, nullptr);
            }
        } else {
            if (q >= 1) {
                const int u = q - 1;
                gemm_phase<32>(sW, pg, 1024,
                               padHi + (q & 1) * SLOT, padLo + (q & 1) * SLOT,
                               dHi + (u & 1) * SLOT, dLo + (u & 1) * SLOT);
                __syncthreads();
                pointwise(pg, gpre2 + (size_t)u * 262144, bsl, c, d0,
                          dHi + ((u + 1) & 1) * SLOT, dLo + ((u + 1) & 1) * SLOT,
                          doutW + (size_t)u * SLOT);
            }
        }
        gbar(bar_cnt, bar_gen);
    }
}

// ===========================================================================
__global__ void add2(const float* __restrict__ a, const float* __restrict__ b,
                     float* __restrict__ o, int n)
{
    const int i = blockIdx.x * 256 + threadIdx.x;
    if (i < n) o[i] = a[i] + b[i];
}

__global__ void emb_bos(const float* __restrict__ Wi, const float* __restrict__ bi,
                        float* __restrict__ emb)
{
    const int i = blockIdx.x * 256 + threadIdx.x;  // b*512+d
    const int d = i & 511;
    emb[i] = Wi[(size_t)d * 3000 + 2998] + bi[d];
}

extern "C" void kernel_launch(void* const* d_in, const int* in_sizes, int n_in,
                              void* d_out, int out_size, void* d_ws, size_t ws_size,
                              hipStream_t stream)
{
    (void)in_sizes; (void)n_in; (void)out_size; (void)ws_size;
    const float* in_feat = (const float*)d_in[0];
    const float* ca      = (const float*)d_in[1];
    const float* We_ih   = (const float*)d_in[2];
    const float* We_hh   = (const float*)d_in[3];
    const float* be_ih   = (const float*)d_in[4];
    const float* be_hh   = (const float*)d_in[5];
    const float* Wd_ih   = (const float*)d_in[6];
    const float* Wd_hh   = (const float*)d_in[7];
    const float* bd_ih   = (const float*)d_in[8];
    const float* bd_hh   = (const float*)d_in[9];
    const float* Wi      = (const float*)d_in[10];
    const float* bi      = (const float*)d_in[11];
    const float* Wo      = (const float*)d_in[12];
    const float* bo      = (const float*)d_in[13];
    float* out = (float*)d_out;
    float* ws  = (float*)d_ws;

    // ---- workspace layout (floats) ----
    float* be    = ws;                                  // 2048
    float* bd    = be + 2048;                           // 2048
    float* gpreE = bd + 2048;                           // 80*128*2048 = 20.97M
    float* gpre2 = gpreE + (size_t)80 * 262144;         // 44*128*2048 = 11.53M
    float* emb   = gpre2 + (size_t)44 * 262144;         // 5632*512
    float* doutW = emb + (size_t)5632 * 512;            // 5632*512
    float* bf16z = doutW + (size_t)5632 * 512;          // bf16 arrays below
    __bf16* encHi = (__bf16*)bf16z;                     // 2 slots
    __bf16* encLo = encHi + 2 * SLOT;
    __bf16* padHi = encLo + 2 * SLOT;
    __bf16* padLo = padHi + 2 * SLOT;
    __bf16* dHi   = padLo + 2 * SLOT;
    __bf16* dLo   = dHi + 2 * SLOT;
    unsigned* bar = (unsigned*)(dLo + 2 * SLOT);        // 2 u32

    add2<<<dim3(8), dim3(256), 0, stream>>>(be_ih, be_hh, be, 2048);
    add2<<<dim3(8), dim3(256), 0, stream>>>(bd_ih, bd_hh, bd, 2048);

    hipMemsetAsync(encHi, 0, SLOT * 2, stream);   // enc h slot0 = 0
    hipMemsetAsync(encLo, 0, SLOT * 2, stream);
    hipMemsetAsync(dHi,   0, SLOT * 2, stream);   // dec h slot0 = 0
    hipMemsetAsync(dLo,   0, SLOT * 2, stream);
    hipMemsetAsync(bar,   0, 8, stream);

    emb_bos<<<dim3(256), dim3(256), 0, stream>>>(Wi, bi, emb);

    // encoder input projection for all 80 steps (includes be)
    gemm_split<true, false><<<dim3(80, 16), dim3(256), 0, stream>>>(
        in_feat, 4096, We_ih, 4096, gpreE, 2048, be, 10240, 2048, 4096);

    // embedding: correct_answer[1:44] @ Wi^T + bi
    gemm_split<true, false><<<dim3(43, 4), dim3(256), 0, stream>>>(
        ca + (size_t)128 * 3000, 3000, Wi, 3000, emb + (size_t)128 * 512, 512, bi,
        5504, 512, 3000);

    // dec2 precomputable gate term: emb @ Wd_ih[:, :512]^T + bd
    gemm_split<true, false><<<dim3(44, 16), dim3(256), 0, stream>>>(
        emb, 512, Wd_ih, 1024, gpre2, 2048, bd, 5632, 2048, 512);

    // all 248 LSTM steps in one persistent kernel
    recurrence_kernel<<<dim3(NBLK), dim3(256), 0, stream>>>(
        gpreE, gpre2, We_hh, Wd_ih, Wd_hh, be, bd,
        encHi, encLo, padHi, padLo, dHi, dLo, doutW, bar, bar + 1);

    // words = dec_out @ Wo^T + bo
    gemm_split<true, false><<<dim3(44, 24), dim3(256), 0, stream>>>(
        doutW, 512, Wo, 512, out, 3000, bo, 5632, 3000, 512);
}